// Round 6
// baseline (2975.005 us; speedup 1.0000x reference)
//
#include <hip/hip_runtime.h>
#include <hip/hip_bf16.h>

// Problem constants (reference: T=2048, B=64, D=256, H=256)
constexpr int T = 2048;
constexpr int B = 64;
constexpr int D = 256;
constexpr int H = 256;
constexpr int M = T * B;        // 131072 GEMM rows
constexpr int N2 = 2 * H;       // 512 output feature dim (u1 | u2)

#define GLOBAL_AS __attribute__((address_space(1)))
#define LDS_AS    __attribute__((address_space(3)))

// ---------------------------------------------------------------------------
// Projection GEMM: out[m][n] = xs[m,:] @ [Wx1 | Wx2][:, n] into d_out's ys.
// 128x128 tile, BK=32, 256 threads, 2x2 quadrants of 4x4 micro-tiles
// (conflict-free LDS reads). NEW vs round 4: register-staged prefetch —
// next k0-tile's global loads are issued BEFORE the inner loop so HBM
// latency hides under the 2048-FMA compute phase (T14 pattern).
// ---------------------------------------------------------------------------
constexpr int BK = 32;
constexpr int LDSW = 132;       // padded row stride in floats

__global__ __launch_bounds__(256, 4) void proj_gemm(
        const float* __restrict__ xs,
        const float* __restrict__ Wx1,
        const float* __restrict__ Wx2,
        float* __restrict__ out) {
    __shared__ float As[BK][LDSW];   // k-major: As[k][m]
    __shared__ float Bs[BK][LDSW];   // Bs[k][n]

    const int bm = blockIdx.x;
    const int bn = blockIdx.y;
    const float* W = (bn < 2) ? Wx1 : Wx2;
    const int ncol0w = (bn & 1) * 128;
    const int m0 = bm * 128;

    const int tid = threadIdx.x;
    const int tx = tid & 15;
    const int ty = tid >> 4;

    const int ar = tid >> 1;           // A stage: row 0..127
    const int akc = (tid & 1) * 16;    // A stage: k-offset 0/16

    float2 acc[2][2][4][2];
    #pragma unroll
    for (int qi = 0; qi < 2; ++qi)
        #pragma unroll
        for (int qj = 0; qj < 2; ++qj)
            #pragma unroll
            for (int i = 0; i < 4; ++i)
                #pragma unroll
                for (int jp = 0; jp < 2; ++jp)
                    acc[qi][qj][i][jp] = make_float2(0.f, 0.f);

    float4 aReg[4];   // staged A: rows ar, k akc..akc+15
    float4 bReg[4];   // staged B: 4 float4s of the 32x128 tile

    auto load_tile = [&](int k0) {
        const float* asrc = &xs[(size_t)(m0 + ar) * D + k0 + akc];
        #pragma unroll
        for (int q = 0; q < 4; ++q)
            aReg[q] = *(const float4*)(asrc + q * 4);
        #pragma unroll
        for (int q = 0; q < 4; ++q) {
            const int idx = tid + 256 * q;
            const int r = idx >> 5;
            const int c = (idx & 31) * 4;
            bReg[q] = *(const float4*)&W[(size_t)(k0 + r) * H + ncol0w + c];
        }
    };
    auto store_tile = [&]() {
        #pragma unroll
        for (int q = 0; q < 4; ++q) {
            As[akc + q * 4 + 0][ar] = aReg[q].x;
            As[akc + q * 4 + 1][ar] = aReg[q].y;
            As[akc + q * 4 + 2][ar] = aReg[q].z;
            As[akc + q * 4 + 3][ar] = aReg[q].w;
        }
        #pragma unroll
        for (int q = 0; q < 4; ++q) {
            const int idx = tid + 256 * q;
            const int r = idx >> 5;
            const int c = (idx & 31) * 4;
            *(float4*)&Bs[r][c] = bReg[q];
        }
    };

    load_tile(0);
    store_tile();
    __syncthreads();

    for (int k0 = 0; k0 < D; k0 += BK) {
        // issue next tile's global loads — they drain during the inner loop
        const bool more = (k0 + BK) < D;
        if (more) load_tile(k0 + BK);

        #pragma unroll
        for (int k = 0; k < BK; ++k) {
            const float4 a0 = *(const float4*)&As[k][ty * 4];
            const float4 a1 = *(const float4*)&As[k][64 + ty * 4];
            const float4 b0 = *(const float4*)&Bs[k][tx * 4];
            const float4 b1 = *(const float4*)&Bs[k][64 + tx * 4];
            const float av[2][4] = {{a0.x, a0.y, a0.z, a0.w},
                                    {a1.x, a1.y, a1.z, a1.w}};
            const float2 bv[2][2] = {{make_float2(b0.x, b0.y), make_float2(b0.z, b0.w)},
                                     {make_float2(b1.x, b1.y), make_float2(b1.z, b1.w)}};
            #pragma unroll
            for (int qi = 0; qi < 2; ++qi)
                #pragma unroll
                for (int i = 0; i < 4; ++i) {
                    const float a = av[qi][i];
                    #pragma unroll
                    for (int qj = 0; qj < 2; ++qj)
                        #pragma unroll
                        for (int jp = 0; jp < 2; ++jp) {
                            float2& c = acc[qi][qj][i][jp];
                            const float2 b = bv[qj][jp];
                            c.x = fmaf(a, b.x, c.x);
                            c.y = fmaf(a, b.y, c.y);
                        }
                }
        }
        __syncthreads();          // all reads of As/Bs done
        if (more) {
            store_tile();         // vmcnt wait lands here, overlapped w/ loop
            __syncthreads();      // publish new tile
        }
    }

    #pragma unroll
    for (int qi = 0; qi < 2; ++qi) {
        #pragma unroll
        for (int i = 0; i < 4; ++i) {
            const size_t row = (size_t)(m0 + qi * 64 + ty * 4 + i);
            #pragma unroll
            for (int qj = 0; qj < 2; ++qj) {
                const int col = bn * 128 + qj * 64 + tx * 4;
                float4 v;
                v.x = acc[qi][qj][i][0].x;
                v.y = acc[qi][qj][i][0].y;
                v.z = acc[qi][qj][i][1].x;
                v.w = acc[qi][qj][i][1].y;
                *(float4*)&out[row * N2 + col] = v;
            }
        }
    }
}

// ---------------------------------------------------------------------------
// Scan v2 (unchanged, unbenched): producer/consumer wave pair per block.
//   Wave 1 streams u-rows for chunk c+1 into a double-buffered LDS ring via
//   global_load_lds (uniform LDS base + lane*4; per-lane global src). Wave 0
//   consumes chunk c from LDS, runs the serial rotation/ReLU chain, stores
//   ys in place. Loader has no dependent chain -> chunk fully in flight;
//   256 blocks x 32 KB = 8 MB >> BW*latency product -> BW-paced.
// ---------------------------------------------------------------------------
constexpr int LC = 64;           // t-steps per chunk
constexpr int NC = T / LC;       // 32 chunks

__global__ __launch_bounds__(128) void rot_scan(const float* __restrict__ h1,
                                                const float* __restrict__ h2,
                                                const float* __restrict__ w1,
                                                const float* __restrict__ w2,
                                                float* __restrict__ out) {
    __shared__ float ubuf[2][LC][2][64];   // [buf][step][u1/u2][lane] = 64 KB

    const int bid = blockIdx.x;            // 0..255
    const int b = bid >> 2;
    const int h0 = (bid & 3) * 64;
    const int tid = threadIdx.x;
    const int lane = tid & 63;
    const bool is_loader = tid >= 64;
    const size_t ts = (size_t)B * N2;      // t-stride in floats

    float* gbase = out + (size_t)b * N2 + h0 + lane;

    if (is_loader) {
        #pragma unroll 4
        for (int s = 0; s < LC; ++s) {
            const size_t off = (size_t)s * ts;
            __builtin_amdgcn_global_load_lds(
                (const GLOBAL_AS unsigned*)(const void*)(gbase + off),
                (LDS_AS unsigned*)(void*)&ubuf[0][s][0][0], 4, 0, 0);
            __builtin_amdgcn_global_load_lds(
                (const GLOBAL_AS unsigned*)(const void*)(gbase + off + H),
                (LDS_AS unsigned*)(void*)&ubuf[0][s][1][0], 4, 0, 0);
        }
    }

    float c1 = 0.f, c2 = 0.f, p1 = 0.f, p2 = 0.f;
    if (!is_loader) {
        c1 = w1[h0 + lane];
        c2 = w2[h0 + lane];
        p1 = h1[b * H + h0 + lane];
        p2 = h2[b * H + h0 + lane];
    }

    __syncthreads();   // drains loader's vmcnt -> chunk 0 visible

    for (int c = 0; c < NC; ++c) {
        if (is_loader) {
            if (c + 1 < NC) {
                const int nb = (c + 1) & 1;
                #pragma unroll 4
                for (int s = 0; s < LC; ++s) {
                    const size_t off = (size_t)((c + 1) * LC + s) * ts;
                    __builtin_amdgcn_global_load_lds(
                        (const GLOBAL_AS unsigned*)(const void*)(gbase + off),
                        (LDS_AS unsigned*)(void*)&ubuf[nb][s][0][0], 4, 0, 0);
                    __builtin_amdgcn_global_load_lds(
                        (const GLOBAL_AS unsigned*)(const void*)(gbase + off + H),
                        (LDS_AS unsigned*)(void*)&ubuf[nb][s][1][0], 4, 0, 0);
                }
            }
        } else {
            const int cb = c & 1;
            float* orow = gbase + (size_t)(c * LC) * ts;
            #pragma unroll 8
            for (int s = 0; s < LC; ++s) {
                const float u1 = ubuf[cb][s][0][lane];
                const float u2 = ubuf[cb][s][1][lane];
                const float g1 = fmaf(c1, p1, fmaf(-c2, p2, u1));
                const float g2 = fmaf(c2, p1, fmaf(c1, p2, u2));
                p1 = fmaxf(g1, 0.0f);
                p2 = fmaxf(g2, 0.0f);
                orow[0] = p1;
                orow[H] = p2;
                orow += ts;
            }
        }
        __syncthreads();   // publish chunk c+1, retire buf c
    }

    if (!is_loader) {
        float* fin = out + (size_t)T * B * N2;
        fin[b * H + h0 + lane] = p1;               // f1
        fin[B * H + b * H + h0 + lane] = p2;       // f2
    }
}

// ---------------------------------------------------------------------------
extern "C" void kernel_launch(void* const* d_in, const int* in_sizes, int n_in,
                              void* d_out, int out_size, void* d_ws, size_t ws_size,
                              hipStream_t stream) {
    const float* xs  = (const float*)d_in[0];
    const float* h1  = (const float*)d_in[1];
    const float* h2  = (const float*)d_in[2];
    const float* w1  = (const float*)d_in[3];
    const float* w2  = (const float*)d_in[4];
    const float* Wx1 = (const float*)d_in[5];
    const float* Wx2 = (const float*)d_in[6];
    float* out = (float*)d_out;

    // Stage 1: projections straight into the ys region of d_out.
    dim3 ggrid(M / 128, N2 / 128);
    proj_gemm<<<ggrid, 256, 0, stream>>>(xs, Wx1, Wx2, out);

    // Stage 2: producer/consumer in-place scan + final states.
    rot_scan<<<B * H / 64, 128, 0, stream>>>(h1, h2, w1, w2, out);
}

// Round 7
// 874.289 us; speedup vs baseline: 3.4028x; 3.4028x over previous
//
#include <hip/hip_runtime.h>
#include <hip/hip_bf16.h>

// Problem constants (reference: T=2048, B=64, D=256, H=256)
constexpr int T = 2048;
constexpr int B = 64;
constexpr int D = 256;
constexpr int H = 256;
constexpr int M = T * B;        // 131072 GEMM rows
constexpr int N2 = 2 * H;       // 512 output feature dim (u1 | u2)

#define GLOBAL_AS __attribute__((address_space(1)))
#define LDS_AS    __attribute__((address_space(3)))

// ---------------------------------------------------------------------------
// Projection GEMM v3: out[m][n] = xs[m,:] @ [Wx1 | Wx2][:, n] into d_out's ys.
// m97-style structure adapted to fp32 VALU:
//   - double-buffered LINEAR LDS tiles staged via global_load_lds width=16
//     (no staging registers -> cannot spill; round-5 lesson),
//   - one __syncthreads per k-tile; prefetch of tile t+1 issued before the
//     compute of tile t, so HBM latency hides under ~4096 FMA cycles,
//   - A read as b128 along k (4 k-values per read); 4-way bank aliasing on A
//     costs ~19cyc/read but LDS pipe stays well under the 128cyc/k VALU cost.
// 128x128 tile, BK=32, 256 threads, 2x2 quadrants of 4x4 micro-tiles.
// ---------------------------------------------------------------------------
constexpr int BK = 32;
constexpr int NT = D / BK;      // 8 k-tiles

__device__ __forceinline__ float comp4(const float4& v, int kk) {
    return kk == 0 ? v.x : kk == 1 ? v.y : kk == 2 ? v.z : v.w;
}

__global__ __launch_bounds__(256, 2) void proj_gemm(
        const float* __restrict__ xs,
        const float* __restrict__ Wx1,
        const float* __restrict__ Wx2,
        float* __restrict__ out) {
    __shared__ float As[2][128][BK];    // [buf][m][k], 16 KB each, linear
    __shared__ float Bs[2][BK][128];    // [buf][k][n], 16 KB each, linear

    const int bm = blockIdx.x;
    const int bn = blockIdx.y;
    const float* Wb = (bn < 2) ? Wx1 : Wx2;
    const int ncol0w = (bn & 1) * 128;
    const int m0 = bm * 128;

    const int tid = threadIdx.x;
    const int lane = tid & 63;
    const int wave = tid >> 6;          // 0..3
    const int tx = tid & 15;
    const int ty = tid >> 4;

    // Per-lane global source coordinates for staging (fixed; only k0 moves).
    // A instr i covers LDS flat floats [i*256, i*256+256): r=i*8+(lane>>3),
    // c=(lane&7)*4.  B instr i: r=2i+(lane>>5), c=(lane&31)*4.
    const int a_r = lane >> 3;          // + i*8
    const int a_c = (lane & 7) * 4;
    const int b_r = lane >> 5;          // + 2*i
    const int b_c = (lane & 31) * 4;

    float2 acc[2][2][4][2];
    #pragma unroll
    for (int qi = 0; qi < 2; ++qi)
        #pragma unroll
        for (int qj = 0; qj < 2; ++qj)
            #pragma unroll
            for (int i = 0; i < 4; ++i)
                #pragma unroll
                for (int jp = 0; jp < 2; ++jp)
                    acc[qi][qj][i][jp] = make_float2(0.f, 0.f);

#define STAGE_TILE(bufi, k0v)                                                  \
    {                                                                          \
        _Pragma("unroll")                                                      \
        for (int q = 0; q < 4; ++q) {                                          \
            const int i = wave * 4 + q;                                        \
            const float* srcA =                                                \
                xs + (size_t)(m0 + i * 8 + a_r) * D + (k0v) + a_c;             \
            __builtin_amdgcn_global_load_lds(                                  \
                (const GLOBAL_AS unsigned*)(const void*)srcA,                  \
                (LDS_AS unsigned*)(void*)&As[(bufi)][i * 8][0], 16, 0, 0);     \
            const float* srcB =                                                \
                Wb + (size_t)((k0v) + 2 * i + b_r) * H + ncol0w + b_c;         \
            __builtin_amdgcn_global_load_lds(                                  \
                (const GLOBAL_AS unsigned*)(const void*)srcB,                  \
                (LDS_AS unsigned*)(void*)&Bs[(bufi)][2 * i][0], 16, 0, 0);     \
        }                                                                      \
    }

    STAGE_TILE(0, 0);
    __syncthreads();    // drain prologue staging

    for (int t = 0; t < NT; ++t) {
        if (t + 1 < NT) STAGE_TILE((t + 1) & 1, (t + 1) * BK);

        const int cb = t & 1;
        #pragma unroll
        for (int k4 = 0; k4 < BK / 4; ++k4) {
            float4 a4[2][4];
            #pragma unroll
            for (int qi = 0; qi < 2; ++qi)
                #pragma unroll
                for (int i = 0; i < 4; ++i)
                    a4[qi][i] =
                        *(const float4*)&As[cb][qi * 64 + ty * 4 + i][k4 * 4];
            #pragma unroll
            for (int kk = 0; kk < 4; ++kk) {
                const float4 b0 = *(const float4*)&Bs[cb][k4 * 4 + kk][tx * 4];
                const float4 b1 =
                    *(const float4*)&Bs[cb][k4 * 4 + kk][64 + tx * 4];
                const float2 bv[2][2] = {
                    {make_float2(b0.x, b0.y), make_float2(b0.z, b0.w)},
                    {make_float2(b1.x, b1.y), make_float2(b1.z, b1.w)}};
                #pragma unroll
                for (int qi = 0; qi < 2; ++qi)
                    #pragma unroll
                    for (int i = 0; i < 4; ++i) {
                        const float a = comp4(a4[qi][i], kk);
                        #pragma unroll
                        for (int qj = 0; qj < 2; ++qj)
                            #pragma unroll
                            for (int jp = 0; jp < 2; ++jp) {
                                float2& c = acc[qi][qj][i][jp];
                                c.x = fmaf(a, bv[qj][jp].x, c.x);
                                c.y = fmaf(a, bv[qj][jp].y, c.y);
                            }
                    }
            }
        }
        __syncthreads();   // stage t+1 landed; buf t&1 free for overwrite
    }

    #pragma unroll
    for (int qi = 0; qi < 2; ++qi) {
        #pragma unroll
        for (int i = 0; i < 4; ++i) {
            const size_t row = (size_t)(m0 + qi * 64 + ty * 4 + i);
            #pragma unroll
            for (int qj = 0; qj < 2; ++qj) {
                const int col = bn * 128 + qj * 64 + tx * 4;
                float4 v;
                v.x = acc[qi][qj][i][0].x;
                v.y = acc[qi][qj][i][0].y;
                v.z = acc[qi][qj][i][1].x;
                v.w = acc[qi][qj][i][1].y;
                *(float4*)&out[row * N2 + col] = v;
            }
        }
    }
#undef STAGE_TILE
}

// ---------------------------------------------------------------------------
// Scan (unchanged; measured ~260us in round 6): producer/consumer wave pair.
//   Wave 1 streams u-rows for chunk c+1 into a double-buffered LDS ring via
//   global_load_lds; wave 0 consumes chunk c from LDS, runs the serial
//   rotation/ReLU chain, stores ys in place.
// ---------------------------------------------------------------------------
constexpr int LC = 64;           // t-steps per chunk
constexpr int NC = T / LC;       // 32 chunks

__global__ __launch_bounds__(128) void rot_scan(const float* __restrict__ h1,
                                                const float* __restrict__ h2,
                                                const float* __restrict__ w1,
                                                const float* __restrict__ w2,
                                                float* __restrict__ out) {
    __shared__ float ubuf[2][LC][2][64];   // [buf][step][u1/u2][lane] = 64 KB

    const int bid = blockIdx.x;            // 0..255
    const int b = bid >> 2;
    const int h0 = (bid & 3) * 64;
    const int tid = threadIdx.x;
    const int lane = tid & 63;
    const bool is_loader = tid >= 64;
    const size_t ts = (size_t)B * N2;      // t-stride in floats

    float* gbase = out + (size_t)b * N2 + h0 + lane;

    if (is_loader) {
        #pragma unroll 4
        for (int s = 0; s < LC; ++s) {
            const size_t off = (size_t)s * ts;
            __builtin_amdgcn_global_load_lds(
                (const GLOBAL_AS unsigned*)(const void*)(gbase + off),
                (LDS_AS unsigned*)(void*)&ubuf[0][s][0][0], 4, 0, 0);
            __builtin_amdgcn_global_load_lds(
                (const GLOBAL_AS unsigned*)(const void*)(gbase + off + H),
                (LDS_AS unsigned*)(void*)&ubuf[0][s][1][0], 4, 0, 0);
        }
    }

    float c1 = 0.f, c2 = 0.f, p1 = 0.f, p2 = 0.f;
    if (!is_loader) {
        c1 = w1[h0 + lane];
        c2 = w2[h0 + lane];
        p1 = h1[b * H + h0 + lane];
        p2 = h2[b * H + h0 + lane];
    }

    __syncthreads();   // drains loader's vmcnt -> chunk 0 visible

    for (int c = 0; c < NC; ++c) {
        if (is_loader) {
            if (c + 1 < NC) {
                const int nb = (c + 1) & 1;
                #pragma unroll 4
                for (int s = 0; s < LC; ++s) {
                    const size_t off = (size_t)((c + 1) * LC + s) * ts;
                    __builtin_amdgcn_global_load_lds(
                        (const GLOBAL_AS unsigned*)(const void*)(gbase + off),
                        (LDS_AS unsigned*)(void*)&ubuf[nb][s][0][0], 4, 0, 0);
                    __builtin_amdgcn_global_load_lds(
                        (const GLOBAL_AS unsigned*)(const void*)(gbase + off + H),
                        (LDS_AS unsigned*)(void*)&ubuf[nb][s][1][0], 4, 0, 0);
                }
            }
        } else {
            const int cb = c & 1;
            float* orow = gbase + (size_t)(c * LC) * ts;
            #pragma unroll 8
            for (int s = 0; s < LC; ++s) {
                const float u1 = ubuf[cb][s][0][lane];
                const float u2 = ubuf[cb][s][1][lane];
                const float g1 = fmaf(c1, p1, fmaf(-c2, p2, u1));
                const float g2 = fmaf(c2, p1, fmaf(c1, p2, u2));
                p1 = fmaxf(g1, 0.0f);
                p2 = fmaxf(g2, 0.0f);
                orow[0] = p1;
                orow[H] = p2;
                orow += ts;
            }
        }
        __syncthreads();   // publish chunk c+1, retire buf c
    }

    if (!is_loader) {
        float* fin = out + (size_t)T * B * N2;
        fin[b * H + h0 + lane] = p1;               // f1
        fin[B * H + b * H + h0 + lane] = p2;       // f2
    }
}

// ---------------------------------------------------------------------------
extern "C" void kernel_launch(void* const* d_in, const int* in_sizes, int n_in,
                              void* d_out, int out_size, void* d_ws, size_t ws_size,
                              hipStream_t stream) {
    const float* xs  = (const float*)d_in[0];
    const float* h1  = (const float*)d_in[1];
    const float* h2  = (const float*)d_in[2];
    const float* w1  = (const float*)d_in[3];
    const float* w2  = (const float*)d_in[4];
    const float* Wx1 = (const float*)d_in[5];
    const float* Wx2 = (const float*)d_in[6];
    float* out = (float*)d_out;

    // Stage 1: projections straight into the ys region of d_out.
    dim3 ggrid(M / 128, N2 / 128);
    proj_gemm<<<ggrid, 256, 0, stream>>>(xs, Wx1, Wx2, out);

    // Stage 2: producer/consumer in-place scan + final states.
    rot_scan<<<B * H / 64, 128, 0, stream>>>(h1, h2, w1, w2, out);
}

// Round 8
// 553.835 us; speedup vs baseline: 5.3716x; 1.5786x over previous
//
#include <hip/hip_runtime.h>
#include <hip/hip_bf16.h>

// Problem constants (reference: T=2048, B=64, D=256, H=256)
constexpr int T = 2048;
constexpr int B = 64;
constexpr int D = 256;
constexpr int H = 256;
constexpr int M = T * B;        // 131072 GEMM rows
constexpr int N2 = 2 * H;       // 512 output feature dim (u1 | u2)

#define GLOBAL_AS __attribute__((address_space(1)))
#define LDS_AS    __attribute__((address_space(3)))

using bf16x8 = __attribute__((ext_vector_type(8))) short;   // MFMA A/B frag
using f32x4  = __attribute__((ext_vector_type(4))) float;   // MFMA C/D frag

// Split fp32 -> bf16 hi + bf16 lo (truncation; lo captures hi's rounding):
// |x - hi - lo| <= 2^-16 |x|.  3-product MFMA (hi*hi + hi*lo + lo*hi) then
// carries ~2^-16 relative error -> ~1e-4 abs in u, ~1e-3 after the scan.
__device__ __forceinline__ void bf16_split(float f, unsigned short& h,
                                           unsigned short& l) {
    const unsigned u = __builtin_bit_cast(unsigned, f);
    const unsigned hu = u & 0xFFFF0000u;
    h = (unsigned short)(hu >> 16);
    const float r = f - __builtin_bit_cast(float, hu);
    l = (unsigned short)(__builtin_bit_cast(unsigned, r) >> 16);
}

// ---------------------------------------------------------------------------
// Projection GEMM v4 (split-bf16 MFMA):
//   out[m][n] = xs[m,:] @ [Wx1|Wx2][:,n] into d_out's ys region [M][512].
//   128x128 block tile, K-step 32, 256 threads = 4 waves in 2x2, each wave
//   a 64x64 sub-tile = 4x4 MFMA 16x16x32 fragments, 3 MFMAs per fragment
//   (hi*hi, hi*lo, lo*hi).
//   LDS holds fragments in FRAGMENT ORDER ([tile16][lane][8 bf16]) so each
//   fragment load is one conflict-free ds_read_b128. The SAME (lane-group,
//   elem)->k map is used staging A and B, so any mismatch vs the hardware's
//   internal k-slot order is a bijection applied to both operands and
//   cancels in the dot product. Correctness then rests only on:
//   A-row/B-col = lane&15 (standard) and the m89-verified C/D layout
//   (col = lane&15, row = (lane>>4)*4 + reg).
// ---------------------------------------------------------------------------
constexpr int NT = D / 32;      // 8 k-steps

__global__ __launch_bounds__(256, 2) void proj_gemm(
        const float* __restrict__ xs,
        const float* __restrict__ Wx1,
        const float* __restrict__ Wx2,
        float* __restrict__ out) {
    // fragment-order planes: [buf][tile16][lane][8 bf16] = 16 KB each
    __shared__ unsigned short AsH[2][8][64][8];
    __shared__ unsigned short AsL[2][8][64][8];
    __shared__ unsigned short BsH[2][8][64][8];
    __shared__ unsigned short BsL[2][8][64][8];

    const int bn = blockIdx.x;          // 0..3  (adjacent blocks share xs panel)
    const int bm = blockIdx.y;          // 0..1023
    const float* Wb = (bn < 2) ? Wx1 : Wx2;
    const int ncol0w = (bn & 1) * 128;
    const int m0 = bm * 128;

    const int tid = threadIdx.x;
    const int lane = tid & 63;
    const int wave = tid >> 6;
    const int wr = wave >> 1;           // wave row 0..1 (64 rows each)
    const int wc = wave & 1;            // wave col 0..1

    // A staging: thread -> (row am, k-half akh); 4 float4 = k 16 per tile
    const int am = tid >> 1;            // 0..127
    const int akh = tid & 1;
    // B staging: thread -> (col bnl, k-half bkh); 16 scalar rows
    const int bnl = tid & 127;          // 0..127
    const int bkh = tid >> 7;

    f32x4 acc[4][4];
    #pragma unroll
    for (int i = 0; i < 4; ++i)
        #pragma unroll
        for (int j = 0; j < 4; ++j)
            acc[i][j] = f32x4{0.f, 0.f, 0.f, 0.f};

    float4 aS[4];
    float bS[16];

    auto issue_loads = [&](int t) {
        const float* asrc = xs + (size_t)(m0 + am) * D + t * 32 + akh * 16;
        #pragma unroll
        for (int q = 0; q < 4; ++q)
            aS[q] = *(const float4*)(asrc + q * 4);
        const float* bsrc =
            Wb + (size_t)(t * 32 + bkh * 16) * H + ncol0w + bnl;
        #pragma unroll
        for (int r = 0; r < 16; ++r)
            bS[r] = bsrc[(size_t)r * H];
    };

    // k-map used for BOTH A and B: k = 16*(j>>2) + 4*lg + (j&3),
    // lg = lane>>4, j = elem 0..7  (bijection over k=0..31).
    auto cvt_store = [&](int buf) {
        const int gm = am >> 4;
        #pragma unroll
        for (int q = 0; q < 4; ++q) {   // logical k = akh*16 + 4q + i
            const int laneA = (am & 15) | (q << 4);
            unsigned short h0, h1, h2, h3, l0, l1, l2, l3;
            bf16_split(aS[q].x, h0, l0);
            bf16_split(aS[q].y, h1, l1);
            bf16_split(aS[q].z, h2, l2);
            bf16_split(aS[q].w, h3, l3);
            *(ushort4*)&AsH[buf][gm][laneA][akh * 4] = make_ushort4(h0, h1, h2, h3);
            *(ushort4*)&AsL[buf][gm][laneA][akh * 4] = make_ushort4(l0, l1, l2, l3);
        }
        const int gn = bnl >> 4;
        #pragma unroll
        for (int g = 0; g < 4; ++g) {   // logical k = bkh*16 + 4g + i
            const int laneB = (bnl & 15) | (g << 4);
            unsigned short h0, h1, h2, h3, l0, l1, l2, l3;
            bf16_split(bS[g * 4 + 0], h0, l0);
            bf16_split(bS[g * 4 + 1], h1, l1);
            bf16_split(bS[g * 4 + 2], h2, l2);
            bf16_split(bS[g * 4 + 3], h3, l3);
            *(ushort4*)&BsH[buf][gn][laneB][bkh * 4] = make_ushort4(h0, h1, h2, h3);
            *(ushort4*)&BsL[buf][gn][laneB][bkh * 4] = make_ushort4(l0, l1, l2, l3);
        }
    };

    issue_loads(0);
    cvt_store(0);
    __syncthreads();

    for (int t = 0; t < NT; ++t) {
        const bool more = (t + 1) < NT;
        if (more) issue_loads(t + 1);   // HBM latency hides under MFMAs

        const int cb = t & 1;
        bf16x8 ah[4], al[4];
        #pragma unroll
        for (int mt = 0; mt < 4; ++mt) {
            ah[mt] = *(const bf16x8*)&AsH[cb][wr * 4 + mt][lane][0];
            al[mt] = *(const bf16x8*)&AsL[cb][wr * 4 + mt][lane][0];
        }
        #pragma unroll
        for (int nt = 0; nt < 4; ++nt) {
            const bf16x8 bh = *(const bf16x8*)&BsH[cb][wc * 4 + nt][lane][0];
            const bf16x8 bl = *(const bf16x8*)&BsL[cb][wc * 4 + nt][lane][0];
            #pragma unroll
            for (int mt = 0; mt < 4; ++mt) {
                acc[mt][nt] = __builtin_amdgcn_mfma_f32_16x16x32_bf16(
                    ah[mt], bh, acc[mt][nt], 0, 0, 0);
                acc[mt][nt] = __builtin_amdgcn_mfma_f32_16x16x32_bf16(
                    ah[mt], bl, acc[mt][nt], 0, 0, 0);
                acc[mt][nt] = __builtin_amdgcn_mfma_f32_16x16x32_bf16(
                    al[mt], bh, acc[mt][nt], 0, 0, 0);
            }
        }
        if (more) cvt_store((t + 1) & 1);   // waits vmcnt here, not earlier
        __syncthreads();
    }

    // C/D layout (m89-verified): col = lane&15, row = (lane>>4)*4 + reg
    const int crow = (lane >> 4) * 4;
    const int ccol = lane & 15;
    #pragma unroll
    for (int mt = 0; mt < 4; ++mt) {
        #pragma unroll
        for (int nt = 0; nt < 4; ++nt) {
            const size_t rbase = (size_t)(m0 + wr * 64 + mt * 16 + crow);
            const int col = bn * 128 + wc * 64 + nt * 16 + ccol;
            #pragma unroll
            for (int r = 0; r < 4; ++r)
                out[(rbase + r) * N2 + col] = acc[mt][nt][r];
        }
    }
}

// ---------------------------------------------------------------------------
// Scan (unchanged; ~260-300us measured): producer/consumer wave pair.
//   Wave 1 streams u-rows for chunk c+1 into a double-buffered LDS ring via
//   global_load_lds; wave 0 consumes chunk c from LDS, runs the serial
//   rotation/ReLU chain, stores ys in place.
// ---------------------------------------------------------------------------
constexpr int LC = 64;           // t-steps per chunk
constexpr int NC = T / LC;       // 32 chunks

__global__ __launch_bounds__(128) void rot_scan(const float* __restrict__ h1,
                                                const float* __restrict__ h2,
                                                const float* __restrict__ w1,
                                                const float* __restrict__ w2,
                                                float* __restrict__ out) {
    __shared__ float ubuf[2][LC][2][64];   // [buf][step][u1/u2][lane] = 64 KB

    const int bid = blockIdx.x;            // 0..255
    const int b = bid >> 2;
    const int h0 = (bid & 3) * 64;
    const int tid = threadIdx.x;
    const int lane = tid & 63;
    const bool is_loader = tid >= 64;
    const size_t ts = (size_t)B * N2;      // t-stride in floats

    float* gbase = out + (size_t)b * N2 + h0 + lane;

    if (is_loader) {
        #pragma unroll 4
        for (int s = 0; s < LC; ++s) {
            const size_t off = (size_t)s * ts;
            __builtin_amdgcn_global_load_lds(
                (const GLOBAL_AS unsigned*)(const void*)(gbase + off),
                (LDS_AS unsigned*)(void*)&ubuf[0][s][0][0], 4, 0, 0);
            __builtin_amdgcn_global_load_lds(
                (const GLOBAL_AS unsigned*)(const void*)(gbase + off + H),
                (LDS_AS unsigned*)(void*)&ubuf[0][s][1][0], 4, 0, 0);
        }
    }

    float c1 = 0.f, c2 = 0.f, p1 = 0.f, p2 = 0.f;
    if (!is_loader) {
        c1 = w1[h0 + lane];
        c2 = w2[h0 + lane];
        p1 = h1[b * H + h0 + lane];
        p2 = h2[b * H + h0 + lane];
    }

    __syncthreads();   // drains loader's vmcnt -> chunk 0 visible

    for (int c = 0; c < NC; ++c) {
        if (is_loader) {
            if (c + 1 < NC) {
                const int nb = (c + 1) & 1;
                #pragma unroll 4
                for (int s = 0; s < LC; ++s) {
                    const size_t off = (size_t)((c + 1) * LC + s) * ts;
                    __builtin_amdgcn_global_load_lds(
                        (const GLOBAL_AS unsigned*)(const void*)(gbase + off),
                        (LDS_AS unsigned*)(void*)&ubuf[nb][s][0][0], 4, 0, 0);
                    __builtin_amdgcn_global_load_lds(
                        (const GLOBAL_AS unsigned*)(const void*)(gbase + off + H),
                        (LDS_AS unsigned*)(void*)&ubuf[nb][s][1][0], 4, 0, 0);
                }
            }
        } else {
            const int cb = c & 1;
            float* orow = gbase + (size_t)(c * LC) * ts;
            #pragma unroll 8
            for (int s = 0; s < LC; ++s) {
                const float u1 = ubuf[cb][s][0][lane];
                const float u2 = ubuf[cb][s][1][lane];
                const float g1 = fmaf(c1, p1, fmaf(-c2, p2, u1));
                const float g2 = fmaf(c2, p1, fmaf(c1, p2, u2));
                p1 = fmaxf(g1, 0.0f);
                p2 = fmaxf(g2, 0.0f);
                orow[0] = p1;
                orow[H] = p2;
                orow += ts;
            }
        }
        __syncthreads();   // publish chunk c+1, retire buf c
    }

    if (!is_loader) {
        float* fin = out + (size_t)T * B * N2;
        fin[b * H + h0 + lane] = p1;               // f1
        fin[B * H + b * H + h0 + lane] = p2;       // f2
    }
}

// ---------------------------------------------------------------------------
extern "C" void kernel_launch(void* const* d_in, const int* in_sizes, int n_in,
                              void* d_out, int out_size, void* d_ws, size_t ws_size,
                              hipStream_t stream) {
    const float* xs  = (const float*)d_in[0];
    const float* h1  = (const float*)d_in[1];
    const float* h2  = (const float*)d_in[2];
    const float* w1  = (const float*)d_in[3];
    const float* w2  = (const float*)d_in[4];
    const float* Wx1 = (const float*)d_in[5];
    const float* Wx2 = (const float*)d_in[6];
    float* out = (float*)d_out;

    // Stage 1: split-bf16 MFMA projections into d_out's ys region.
    dim3 ggrid(N2 / 128, M / 128);   // x = bn so xs-sharing blocks are adjacent
    proj_gemm<<<ggrid, 256, 0, stream>>>(xs, Wx1, Wx2, out);

    // Stage 2: producer/consumer in-place scan + final states.
    rot_scan<<<B * H / 64, 128, 0, stream>>>(h1, h2, w1, w2, out);
}